// Round 10
// baseline (191.429 us; speedup 1.0000x reference)
//
#include <hip/hip_runtime.h>
#include <stdint.h>

typedef unsigned long long u64;
typedef unsigned int u32;
typedef unsigned short u16;

#define FH 37
#define FW 62
#define NA 9
#define NPRED 20646        // FH*FW*NA  (< 65536 -> u16 index fits)
#define BS 4
#define KEEP_PRE 6000
#define KEEP_POST 300
#define NBINS 4096         // coarse: sign + 8-bit exp + 3 mantissa bits
#define SELCAP 3072        // ranks resolved per tranche
#define SLOTN 6144
#define FB_BASE 4608       // slots [FB_BASE, SLOTN) = fallback-bin region
#define NFB 640
#define NCHUNK 21          // ceil(20646/1024)
#define FSLOTS 32          // coarse bins covered by the fine map
#define FSUB 64            // fine sub-bins per coarse bin (bits [14:20))

// ---- LDS arena (bytes). Arena C reused: {compactM/N, fineH/S/C} -> {cbox, carea}
#define L_HIST    0u         // u32[4096]
#define L_SUF     16384u     // u32[4096]
#define L_C       32768u
#define L_CM      (L_C + 0u)       // u32[6144] compactM   (24K)
#define L_CN      (L_C + 24576u)   // u16[6144] compactN   (12K)
#define L_FINEH   (L_C + 36864u)   // u32[2048]            (8K)
#define L_FINES   (L_C + 45056u)   // u32[2048]            (8K)
#define L_FINEC   (L_C + 53248u)   // u32[2048]            (8K)
#define L_FBCUR   (L_C + 61440u)   // u32[640]             (2.5K, not overlaid)
#define L_CBOX    (L_C + 0u)       // float4[3072]         (48K, overlays CM/CN/FINEH+)
#define L_CAREA   (L_C + 49152u)   // f32[3072]            (12K, overlays FINES tail+FINEC)
#define L_SLOTM   96768u     // u32[6144] (24K)
#define L_SLOTN   121344u    // u16[6144] (12K)
#define L_PERM    133632u    // u32[3072] (12K)
#define L_KBOX    145920u    // float4[300]
#define L_KAREA   150720u    // f32[300]
#define L_WSUM    151920u    // u32[16]
#define L_SCAL    151984u    // u32[8]: 0 binLo, 1 binHi, 2 cnt, 3 npos, 4 ccnt
#define L_AW      152016u    // u64[32] (parity dbuf)
#define L_MROW    152272u    // u64[64]
#define LDS_TOTAL 152832u

// ---------------------------------------------------------------------------
__device__ __forceinline__ u32 mapbits(float p) {
  u32 u = __float_as_uint(p);
  return (u & 0x80000000u) ? ~u : (u | 0x80000000u);   // order-preserving map
}
__device__ __forceinline__ u64 readlane64(u64 v, int srcLane) {
  u32 lo = __builtin_amdgcn_readlane((u32)v, srcLane);
  u32 hi = __builtin_amdgcn_readlane((u32)(v >> 32), srcLane);
  return ((u64)hi << 32) | lo;
}
// suppression test — textually identical op structure to rounds 0-7 (absmax=0)
__device__ __forceinline__ bool iou_sup(float kx1, float ky1, float kx2, float ky2,
                                        float ka, float cx1, float cy1,
                                        float cx2, float cy2, float ca) {
  float wx = fmaxf(fminf(kx2, cx2) - fmaxf(kx1, cx1), 0.f);
  float wy = fmaxf(fminf(ky2, cy2) - fmaxf(ky1, cy1), 0.f);
  float inter = wx * wy;
  float un = ka + ca - inter;
  return inter > 0.7f * fmaxf(un, 1e-9f);
}
// box decode — textually identical formula to rounds 0-7 (absmax=0)
__device__ __forceinline__ float4 decode_box(u32 n, float4 d, float W, float H) {
  int a = (int)(n % NA);
  int cell = (int)(n / NA);
  int x = cell % FW;
  int y = cell / FW;
  int si = a % 3, ri = a / 3;
  float s = (si==0) ? 8.f : ((si==1) ? 16.f : 32.f);
  float r = (ri==0) ? 0.5f : ((ri==1) ? 1.0f : 2.0f);
  float aw = s * sqrtf(1.0f / r);
  float ah = s * sqrtf(r);
  float gx = (float)x * 16.f, gy = (float)y * 16.f;
  float x1d = gx - 0.5f*aw, x2d = gx + 0.5f*aw;
  float y1d = gy - 0.5f*ah, y2d = gy + 0.5f*ah;
  float w = x2d - x1d, h = y2d - y1d;
  float cx = x1d + 0.5f*w, cy = y1d + 0.5f*h;
  float pcx = d.x*w + cx, pcy = d.y*h + cy;
  float pw = expf(d.z)*w, ph = expf(d.w)*h;
  float bx1 = fminf(fmaxf(pcx - 0.5f*pw, 0.f), W);
  float by1 = fminf(fmaxf(pcy - 0.5f*ph, 0.f), H);
  float bx2 = fminf(fmaxf(pcx + 0.5f*pw, 0.f), W);
  float by2 = fminf(fmaxf(pcy + 0.5f*ph, 0.f), H);
  return make_float4(bx1, by1, bx2, by2);
}

// ---------------------------------------------------------------------------
__global__ void __launch_bounds__(1024) detect_kernel(
    const float* __restrict__ preds, const float4* __restrict__ regs4,
    const int* __restrict__ ih, const int* __restrict__ iw,
    float4* __restrict__ out)
{
  __shared__ __align__(16) char smem[LDS_TOTAL];
  u32*    histL  = (u32*)(smem + L_HIST);
  u32*    sufL   = (u32*)(smem + L_SUF);
  u32*    compM  = (u32*)(smem + L_CM);
  u16*    compN  = (u16*)(smem + L_CN);
  u32*    fineH  = (u32*)(smem + L_FINEH);
  u32*    fineS  = (u32*)(smem + L_FINES);
  u32*    fineC  = (u32*)(smem + L_FINEC);
  u32*    fbCur  = (u32*)(smem + L_FBCUR);
  float4* cboxL  = (float4*)(smem + L_CBOX);
  float*  careaL = (float*)(smem + L_CAREA);
  u32*    slotM  = (u32*)(smem + L_SLOTM);
  u16*    slotN  = (u16*)(smem + L_SLOTN);
  u32*    perm   = (u32*)(smem + L_PERM);
  float4* kbox   = (float4*)(smem + L_KBOX);
  float*  karea  = (float*)(smem + L_KAREA);
  u32*    wsum   = (u32*)(smem + L_WSUM);
  u32*    scal   = (u32*)(smem + L_SCAL);
  u64*    aw     = (u64*)(smem + L_AW);
  u64*    mrow   = (u64*)(smem + L_MROW);

  const int b = blockIdx.x;
  const int t = threadIdx.x;
  const int lane = t & 63;
  const int wv = t >> 6;
  const float* pb = preds + b*NPRED;
  const float4* rb = regs4 + b*NPRED;
  const float W = (float)(*iw), H = (float)(*ih);
  float4* ob = out + b*KEEP_POST;
  const float4 zero = make_float4(0.f, 0.f, 0.f, 0.f);

  // ---- S0: zero coarse hist + control ------------------------------------
  ((uint4*)histL)[t] = make_uint4(0,0,0,0);
  if (t == 0) { scal[2] = 0; scal[3] = 0; }
  __syncthreads();

  // ---- S1: coarse hist + per-thread npos count (no ballots) ---------------
  u32 mypos = 0;
  #pragma unroll 4
  for (int c = 0; c < NCHUNK; ++c) {
    int n = c*1024 + t;
    if (n < NPRED) {
      float p = pb[n];
      mypos += (p > 0.0f) ? 1u : 0u;
      atomicAdd(&histL[mapbits(p) >> 20], 1u);
    }
  }
  __syncthreads();

  // ---- S2: coarse suffix scan + npos reduce -------------------------------
  {
    uint4 h = ((const uint4*)histL)[t];
    u32 s = h.x + h.y + h.z + h.w;
    u32 sf = s;
    u32 mp = mypos;
    #pragma unroll
    for (int off = 1; off < 64; off <<= 1) {
      u32 o = __shfl_down(sf, off, 64);
      if (lane + off < 64) sf += o;
      mp += __shfl_down(mp, off, 64);
    }
    if (lane == 0) { wsum[wv] = sf; atomicAdd(&scal[3], mp); }
    __syncthreads();
    u32 hi = 0;
    #pragma unroll
    for (int w2 = 0; w2 < 16; ++w2) hi += (w2 > wv) ? wsum[w2] : 0u;
    u32 St = hi + (sf - s);
    uint4 sv;
    sv.w = St; sv.z = St + h.w; sv.y = sv.z + h.z; sv.x = sv.y + h.y;
    ((uint4*)sufL)[t] = sv;
  }
  __syncthreads();

  // ---- tranche loop (tranche 1 runs only if NMS starves before 300) ------
  #pragma unroll 1
  for (int tr = 0; tr < 2; ++tr) {
    const u32 winStart = (u32)tr * SELCAP;
    const u32 winEnd = winStart + SELCAP;
    const int rowLimit = (KEEP_PRE - (int)winStart < (int)SELCAP)
                           ? (KEEP_PRE - (int)winStart) : (int)SELCAP;

    if (t == 0) { scal[0] = 0xFFFFFFFFu; scal[1] = 0u; scal[4] = 0u; }
    __syncthreads();
    #pragma unroll
    for (int q = 0; q < 4; ++q) {
      int v = 4*t + q;
      u32 hv = histL[v], sv = sufL[v];
      if (hv && sv < winEnd && sv + hv > winStart) {
        atomicMin(&scal[0], (u32)v);
        atomicMax(&scal[1], (u32)v);
      }
    }
    __syncthreads();
    const u32 binLo = scal[0], binHi = scal[1];
    u32 cBase = binLo;
    if (binHi - binLo >= FSLOTS) cBase = binHi - (FSLOTS - 1);
    const u32 S_top = sufL[binHi];                     // # in coarse bins > binHi
    const u32 S_cb = (cBase > 0) ? sufL[cBase-1] : 0;  // # in bins >= cBase
    const u32 rebWinEnd = winEnd - S_top;
    const u32 fineCap = (cBase == binLo) ? (u32)SLOTN : (u32)FB_BASE;

    // ---- T1: init fine hist + slots + fallback cursors --------------------
    fineH[2*t] = 0; fineH[2*t+1] = 0;
    #pragma unroll
    for (int q = 0; q < 6; ++q) slotM[q*1024 + t] = 0;
    #pragma unroll
    for (int q = 0; q < 3; ++q) ((u32*)slotN)[q*1024 + t] = 0;
    if (t < NFB) {
      u32 v = binLo + (u32)t;
      fbCur[t] = (v < cBase) ? (FB_BASE + (sufL[v] - S_cb)) : (u32)SLOTN;
    }
    __syncthreads();

    // ---- T2': fine hist + COMPACT window elements into LDS ---------------
    #pragma unroll 2
    for (int c = 0; c < NCHUNK; ++c) {
      int n = c*1024 + t;
      bool isWin = false;
      u32 m = 0;
      if (n < NPRED) {
        m = mapbits(pb[n]);
        u32 cb = m >> 20;
        isWin = (cb >= binLo && cb <= binHi);
        if (cb >= cBase && cb <= binHi)
          atomicAdd(&fineH[((cb - cBase) << 6) | ((m >> 14) & 0x3F)], 1u);
      }
      u64 bm = __ballot((int)isWin);
      u32 cntw = (u32)__popcll(bm);
      u32 basew = 0;
      if (lane == 0) basew = atomicAdd(&scal[4], cntw);
      basew = __builtin_amdgcn_readlane(basew, 0);
      if (isWin) {
        u32 pos = basew + (u32)__popcll(bm & ((1ull << lane) - 1ull));
        if (pos < (u32)SLOTN) {
          compM[pos] = m;
          compN[pos] = (u16)(~(u32)n);   // n<65536: low 16 bits of ~n keep order
        }
      }
    }
    __syncthreads();

    // ---- T3: fine suffix scan (2048 bins, 2/thread) -----------------------
    {
      u32 f0 = fineH[2*t], f1 = fineH[2*t+1];
      u32 s = f0 + f1;
      u32 sf = s;
      #pragma unroll
      for (int off = 1; off < 64; off <<= 1) {
        u32 o = __shfl_down(sf, off, 64);
        if (lane + off < 64) sf += o;
      }
      if (lane == 0) wsum[wv] = sf;
      __syncthreads();
      u32 hi = 0;
      #pragma unroll
      for (int w2 = 0; w2 < 16; ++w2) hi += (w2 > wv) ? wsum[w2] : 0u;
      u32 St = hi + (sf - s);
      u32 sA = St + f1, sB = St;
      fineS[2*t] = sA; fineS[2*t+1] = sB;
      fineC[2*t] = sA; fineC[2*t+1] = sB;
    }
    __syncthreads();

    // ---- T4': scatter from compact list into slots ------------------------
    {
      u32 tot = scal[4]; if (tot > (u32)SLOTN) tot = (u32)SLOTN;
      for (u32 i = t; i < tot; i += 1024) {
        u32 m = compM[i];
        u16 nl = compN[i];
        u32 cb = m >> 20;
        if (cb >= cBase) {
          u32 F = ((cb - cBase) << 6) | ((m >> 14) & 0x3F);
          if (fineS[F] < rebWinEnd) {
            u32 pos = atomicAdd(&fineC[F], 1u);
            if (pos < fineCap) { slotM[pos] = m; slotN[pos] = nl; }
          }
        } else {
          u32 fo = cb - binLo;
          if (fo < NFB) {
            u32 pos = atomicAdd(&fbCur[fo], 1u);
            if (pos < (u32)SLOTN) { slotM[pos] = m; slotN[pos] = nl; }
          }
        }
      }
    }
    __syncthreads();

    // ---- T5: exact rank -> perm[local rank] -------------------------------
    #pragma unroll
    for (int q = 0; q < 6; ++q) {
      int i = q*1024 + t;
      u32 m = slotM[i];
      u16 nl = slotN[i];
      if ((m | nl) != 0) {               // (0,0) = unwritten (real nl!=0)
        u32 cb = m >> 20;
        u32 base, end, rbase;
        if (cb >= cBase) {
          u32 F = ((cb - cBase) << 6) | ((m >> 14) & 0x3F);
          base = fineS[F];
          end = base + fineH[F]; if (end > fineCap) end = fineCap;
          rbase = S_top + fineS[F];
        } else {
          base = FB_BASE + (sufL[cb] - S_cb);
          end = base + histL[cb]; if (end > (u32)SLOTN) end = (u32)SLOTN;
          rbase = sufL[cb];
        }
        u32 c2 = 0;
        for (u32 j = base; j < end; j += 4) {
          u32 m0 = slotM[j];                      u16 n0 = slotN[j];
          u32 m1 = (j+1<end)?slotM[j+1]:0;        u16 n1 = (j+1<end)?slotN[j+1]:(u16)0;
          u32 m2 = (j+2<end)?slotM[j+2]:0;        u16 n2 = (j+2<end)?slotN[j+2]:(u16)0;
          u32 m3 = (j+3<end)?slotM[j+3]:0;        u16 n3 = (j+3<end)?slotN[j+3]:(u16)0;
          c2 += (u32)((m0 > m) || (m0 == m && n0 > nl));
          c2 += (u32)((m1 > m) || (m1 == m && n1 > nl));
          c2 += (u32)((m2 > m) || (m2 == m && n2 > nl));
          c2 += (u32)((m3 > m) || (m3 == m && n3 > nl));
        }
        int local = (int)(rbase + c2) - (int)winStart;
        if (local >= 0 && local < rowLimit)
          perm[local] = (u32)((u16)(~nl));        // recover element index n
      }
    }
    __syncthreads();

    // ---- T6: decode first 1024 window boxes (lazy-extend in T7) -----------
    int rowCap = (rowLimit < 1024) ? rowLimit : 1024;
    if (t < rowCap) {
      u32 idx = perm[t];
      float4 bx = decode_box(idx, rb[idx], W, H);
      cboxL[t] = bx;
      careaL[t] = (bx.z - bx.x) * (bx.w - bx.y);
    }
    __syncthreads();

    // ---- T7: greedy NMS, 2 barriers/block ---------------------------------
    {
      const int npos = (int)scal[3];
      const int nblk = (rowLimit + 63) >> 6;
      for (int blk = 0; blk < nblk; ++blk) {
        int cnt = (int)scal[2];          // uniform (post-barrier)
        if (cnt >= KEEP_POST) break;
        const int base = blk * 64;

        if (base + 64 > rowCap && base < rowLimit) {   // lazy decode extend
          int lo = rowCap;
          int hi2 = rowCap + 2048; if (hi2 > rowLimit) hi2 = rowLimit;
          for (int r = lo + t; r < hi2; r += 1024) {
            u32 idx = perm[r];
            float4 bx = decode_box(idx, rb[idx], W, H);
            cboxL[r] = bx;
            careaL[r] = (bx.z - bx.x) * (bx.w - bx.y);
          }
          rowCap = hi2;
          __syncthreads();
        }

        const int ci = base + lane;
        const bool valid = (ci < rowLimit);
        float4 cur = cboxL[valid ? ci : 0];
        float carea = careaL[valid ? ci : 0];

        // Phase A: kept-list check, kept indices strided across 16 waves
        int dead = 0;
        #pragma unroll 2
        for (int k = wv; k < cnt; k += 16) {
          float4 kb = kbox[k];
          dead |= (int)iou_sup(kb.x, kb.y, kb.z, kb.w, karea[k],
                               cur.x, cur.y, cur.z, cur.w, carea);
        }
        u64* awb = aw + ((blk & 1) << 4);
        awb[wv] = __ballot(dead);

        // intra-block 64x64 suppression rows, 4 rows per wave (unconditional)
        #pragma unroll
        for (int q = 0; q < 4; ++q) {
          int j = wv*4 + q;
          int jr = base + j; if (jr >= rowLimit) jr = 0;
          float4 bj = cboxL[jr];
          float ja = careaL[jr];
          bool s = iou_sup(bj.x, bj.y, bj.z, bj.w, ja,
                           cur.x, cur.y, cur.z, cur.w, carea);
          u64 bm = __ballot(s);
          if (lane == 0) mrow[j] = bm;
        }
        __syncthreads();                 // bar1: aw + mrow ready

        u64 deadAll = 0;
        #pragma unroll
        for (int k = 0; k < 16; ++k) deadAll |= awb[k];
        int rem = rowLimit - base;
        u64 vm = (rem >= 64) ? ~0ull : ((1ull << rem) - 1ull);
        u64 A = vm & ~deadAll;
        if (A == 0) continue;            // uniform; dead block costs 1 barrier

        // closure: wave 0 bit-sweep; mask rows in registers (lane l = mrow[l])
        if (wv == 0) {
          u64 mreg = mrow[lane];
          int c2 = cnt;
          while (A && c2 < KEEP_POST) {
            int j = (int)__builtin_ctzll(A);
            A &= A - 1;
            A &= ~readlane64(mreg, j);
            if (lane == 0) {
              float4 bj = cboxL[base + j];
              kbox[c2] = bj;
              karea[c2] = careaL[base + j];
              ob[c2] = ((int)(winStart + (u32)(base + j)) < npos) ? bj : zero;
            }
            ++c2;
          }
          if (lane == 0) scal[2] = (u32)c2;
        }
        __syncthreads();                 // bar2: cnt + kbox ready
      }
    }
    __syncthreads();
    if ((int)scal[2] >= KEEP_POST) break;
  }

  // ---- tail zero-fill (d_out is poisoned before every timed launch) ------
  __syncthreads();
  for (int k2 = (int)scal[2] + t; k2 < KEEP_POST; k2 += 1024) ob[k2] = zero;
}

extern "C" void kernel_launch(void* const* d_in, const int* in_sizes, int n_in,
                              void* d_out, int out_size, void* d_ws, size_t ws_size,
                              hipStream_t stream) {
  const float* preds  = (const float*)d_in[0];
  const float4* regs4 = (const float4*)d_in[1];
  const int* ih       = (const int*)d_in[2];
  const int* iw       = (const int*)d_in[3];
  (void)d_ws; (void)ws_size; (void)in_sizes; (void)n_in; (void)out_size;

  detect_kernel<<<dim3(BS), 1024, 0, stream>>>(
      preds, regs4, ih, iw, (float4*)d_out);
}